// Round 4
// baseline (8139.635 us; speedup 1.0000x reference)
//
#include <hip/hip_runtime.h>
#include <hip/hip_bf16.h>
#include <cstdint>

#define SENTW 0x7F7F7F7Fu   // float ~3.39e38; |h|<1 so never produced by LSTM

__device__ __forceinline__ float sigf(float x){ return 1.f/(1.f+expf(-x)); }

// ---------------- embedding: X[s] = concat(word_emb[x[s]], pos_emb[x_pos[s]]) ----------------
__global__ __launch_bounds__(256) void k_embed(
    const int* __restrict__ x, const int* __restrict__ xp,
    const float* __restrict__ we, const float* __restrict__ pe,
    float* __restrict__ X)
{
  const int s = blockIdx.x, t = threadIdx.x;
  float4* xr = (float4*)(X + (size_t)s*1024);
  if (t < 224){                                  // 224*4 = 896 word dims
    const float4* wr = (const float4*)(we + (size_t)x[s]*896);
    xr[t] = wr[t];
  } else {                                       // 32*4 = 128 pos dims
    const float4* pr = (const float4*)(pe + (size_t)xp[s]*128);
    xr[t] = pr[t-224];
  }
}

// ---------------- fp32 GEMM: C[M,N] = A[M,K] * B[N,K]^T + bias[n] + (*cadd) ----------------
// BM=BN=128, BK=16, 256 threads, 8x8 micro-tile.
__global__ __launch_bounds__(256,2) void k_gemm_abT(
    const float* __restrict__ A, const float* __restrict__ B, float* __restrict__ C,
    int M, int N, int K,
    const float* __restrict__ bias, const float* __restrict__ cadd)
{
  __shared__ float As[16][132];
  __shared__ float Bs[16][132];
  const int tid = threadIdx.x;
  const int m0 = blockIdx.y*128, n0 = blockIdx.x*128;
  const int r  = tid>>1, cq = tid&1;       // loader mapping: row r, k-half cq
  const int ty = tid>>4, tx = tid&15;      // compute mapping

  float acc[8][8];
  #pragma unroll
  for (int i=0;i<8;i++)
    #pragma unroll
    for (int j=0;j<8;j++) acc[i][j]=0.f;

  for (int k0=0;k0<K;k0+=16){
    const float* ap = A + (size_t)(m0+r)*K + k0 + cq*8;
    const float* bp = B + (size_t)(n0+r)*K + k0 + cq*8;
    float4 a0 = *(const float4*)ap;
    float4 a1 = *(const float4*)(ap+4);
    float4 b0 = *(const float4*)bp;
    float4 b1 = *(const float4*)(bp+4);
    __syncthreads();   // previous iteration's LDS reads done
    As[cq*8+0][r]=a0.x; As[cq*8+1][r]=a0.y; As[cq*8+2][r]=a0.z; As[cq*8+3][r]=a0.w;
    As[cq*8+4][r]=a1.x; As[cq*8+5][r]=a1.y; As[cq*8+6][r]=a1.z; As[cq*8+7][r]=a1.w;
    Bs[cq*8+0][r]=b0.x; Bs[cq*8+1][r]=b0.y; Bs[cq*8+2][r]=b0.z; Bs[cq*8+3][r]=b0.w;
    Bs[cq*8+4][r]=b1.x; Bs[cq*8+5][r]=b1.y; Bs[cq*8+6][r]=b1.z; Bs[cq*8+7][r]=b1.w;
    __syncthreads();
    #pragma unroll
    for (int k=0;k<16;k++){
      float4 av0 = *(const float4*)&As[k][ty*8];
      float4 av1 = *(const float4*)&As[k][ty*8+4];
      float4 bv0 = *(const float4*)&Bs[k][tx*8];
      float4 bv1 = *(const float4*)&Bs[k][tx*8+4];
      float a[8]={av0.x,av0.y,av0.z,av0.w,av1.x,av1.y,av1.z,av1.w};
      float b[8]={bv0.x,bv0.y,bv0.z,bv0.w,bv1.x,bv1.y,bv1.z,bv1.w};
      #pragma unroll
      for (int i=0;i<8;i++)
        #pragma unroll
        for (int j=0;j<8;j++)
          acc[i][j] = fmaf(a[i],b[j],acc[i][j]);
    }
  }

  float cb = cadd ? *cadd : 0.f;
  float bv[8];
  if (bias){
    float4 t0 = *(const float4*)&bias[n0+tx*8];
    float4 t1 = *(const float4*)&bias[n0+tx*8+4];
    bv[0]=t0.x; bv[1]=t0.y; bv[2]=t0.z; bv[3]=t0.w;
    bv[4]=t1.x; bv[5]=t1.y; bv[6]=t1.z; bv[7]=t1.w;
  } else {
    #pragma unroll
    for (int j=0;j<8;j++) bv[j]=0.f;
  }
  #pragma unroll
  for (int i=0;i<8;i++){
    float* cp = C + (size_t)(m0+ty*8+i)*N + n0+tx*8;
    float4 o0, o1;
    o0.x=acc[i][0]+bv[0]+cb; o0.y=acc[i][1]+bv[1]+cb;
    o0.z=acc[i][2]+bv[2]+cb; o0.w=acc[i][3]+bv[3]+cb;
    o1.x=acc[i][4]+bv[4]+cb; o1.y=acc[i][5]+bv[5]+cb;
    o1.z=acc[i][6]+bv[6]+cb; o1.w=acc[i][7]+bv[7]+cb;
    *(float4*)cp = o0; *(float4*)(cp+4) = o1;
  }
}

// ---------------- LSTM scan, one layer, both directions (wave-synchronous) ----
// 256 WGs x 128 threads = 512 independent waves; waves 0..255 fwd, 256..511 bwd.
// Each wave owns 2 hidden units (8 rows of W_hh register-resident: lane = row
// (l>>3) x k-chunk (l&7), 64 weights/lane). Per step each wave polls the FULL
// h[sp] itself (lane l: 4 x u64 atomic loads at dwords 2l+128q), stages into
// wave-PRIVATE double-buffered swizzled LDS (wave-local lgkmcnt ordering only
// -- NO __syncthreads anywhere in the scan loop), then dot + shuffle reduce.
__global__ __launch_bounds__(128,1) void k_lstm_scan(
    const float* __restrict__ pre,   // [1024][4096]: dir*2048 + gate*512 + unit
    const float* __restrict__ Whh,   // [2][2048][512] (this layer)
    float* __restrict__ out)         // [1024][1024]; fwd cols 0..511, bwd 512..1023
{
  const int dir = blockIdx.x >> 7;                    // 0..127 fwd, 128..255 bwd
  const int lw  = threadIdx.x >> 6;                   // wave within WG (0/1)
  const int wv  = ((blockIdx.x & 127) << 1) | lw;     // wave id within dir, 0..255
  const int l   = threadIdx.x & 63;                   // lane
  const int kc  = l & 7;          // k-chunk (64 floats)
  const int rl  = l >> 3;         // local row 0..7
  const int gate= rl & 3;         // i,f,g,o
  const int ul  = rl >> 2;        // local unit 0..1
  const int unit= wv*2 + ul;
  const int grow= gate*512 + unit;

  // wave-private swizzled LDS: logical h[i] at slot (i>>6)*68 + (i&63);
  // read base kc*68 -> start banks 0,4,..,28 -> conflict-free b128 reads.
  __shared__ __align__(16) float hsh[2][2][544];      // [wave][buf][slot]

  // register-resident weights: this thread's 64 elements of its row
  float wreg[64];
  {
    const float* wp = Whh + ((size_t)dir*2048 + grow)*512 + kc*64;
    #pragma unroll
    for (int j=0;j<16;j++){
      float4 q = *(const float4*)(wp + 4*j);
      wreg[4*j+0]=q.x; wreg[4*j+1]=q.y; wreg[4*j+2]=q.z; wreg[4*j+3]=q.w;
    }
  }

  unsigned* ob = (unsigned*)out;
  const float* prebase = pre + (size_t)dir*2048 + grow;
  float c = 0.f;
  const int base = l & 32;        // wave-lane base of this unit's gate group
  const int chi  = l >> 5;        // chunk parity contribution of this lane
  const int wb   = (2*l) & 63;    // within-chunk offset of this lane's pair

  for (int t=0;t<1024;t++){
    const int s  = dir ? (1023 - t) : t;
    const int sp = dir ? (s + 1) : (s - 1);

    // prefetch input-projection value (independent of h -> issues before poll)
    float preval = 0.f;
    if (kc==0) preval = prebase[(size_t)s*4096];

    float accv = 0.f;
    if (t > 0){
      // poll the full previous h: lane l covers dwords {2l,2l+1}+128q, q=0..3
      unsigned long long* hp =
          (unsigned long long*)(ob + (size_t)sp*1024 + dir*512) + l;
      unsigned long long v0,v1,v2,v3;
      for(;;){
        v0 = __hip_atomic_load(hp+  0, __ATOMIC_RELAXED, __HIP_MEMORY_SCOPE_AGENT);
        v1 = __hip_atomic_load(hp+ 64, __ATOMIC_RELAXED, __HIP_MEMORY_SCOPE_AGENT);
        v2 = __hip_atomic_load(hp+128, __ATOMIC_RELAXED, __HIP_MEMORY_SCOPE_AGENT);
        v3 = __hip_atomic_load(hp+192, __ATOMIC_RELAXED, __HIP_MEMORY_SCOPE_AGENT);
        unsigned ok = 1u;
        ok &= (unsigned)((unsigned)v0 != SENTW) & (unsigned)((unsigned)(v0>>32) != SENTW);
        ok &= (unsigned)((unsigned)v1 != SENTW) & (unsigned)((unsigned)(v1>>32) != SENTW);
        ok &= (unsigned)((unsigned)v2 != SENTW) & (unsigned)((unsigned)(v2>>32) != SENTW);
        ok &= (unsigned)((unsigned)v3 != SENTW) & (unsigned)((unsigned)(v3>>32) != SENTW);
        if (ok) break;
      }
      float* hb = hsh[lw][t & 1];
      // stage into wave-private LDS (swizzled); wave-local ordering via lgkmcnt
      *(float2*)&hb[(0+chi)*68 + wb] =
          make_float2(__uint_as_float((unsigned)v0), __uint_as_float((unsigned)(v0>>32)));
      *(float2*)&hb[(2+chi)*68 + wb] =
          make_float2(__uint_as_float((unsigned)v1), __uint_as_float((unsigned)(v1>>32)));
      *(float2*)&hb[(4+chi)*68 + wb] =
          make_float2(__uint_as_float((unsigned)v2), __uint_as_float((unsigned)(v2>>32)));
      *(float2*)&hb[(6+chi)*68 + wb] =
          make_float2(__uint_as_float((unsigned)v3), __uint_as_float((unsigned)(v3>>32)));

      const float* hv = hb + kc*68;
      float p0=0.f,p1=0.f,p2=0.f,p3=0.f;
      #pragma unroll
      for (int j=0;j<16;j++){
        float4 q = *(const float4*)(hv + 4*j);
        p0 = fmaf(wreg[4*j+0], q.x, p0);
        p1 = fmaf(wreg[4*j+1], q.y, p1);
        p2 = fmaf(wreg[4*j+2], q.z, p2);
        p3 = fmaf(wreg[4*j+3], q.w, p3);
      }
      accv = (p0+p1)+(p2+p3);
      accv += __shfl_xor(accv, 1);
      accv += __shfl_xor(accv, 2);
      accv += __shfl_xor(accv, 4);   // lanes with kc==0 hold the full dot
    }
    // per-gate activation on the head lane of each row (parallel across rows)
    float act = 0.f;
    if (kc==0){
      float g = accv + preval;
      act = (gate==2) ? tanhf(g) : sigf(g);
    }
    // gather the 4 activated gates of this unit (lanes base+{0,8,16,24})
    float ai = __shfl(act, base+0);
    float af = __shfl(act, base+8);
    float ag = __shfl(act, base+16);
    float ao = __shfl(act, base+24);
    if ((l&31)==0){
      c = af*c + ai*ag;
      float h = ao*tanhf(c);
      __hip_atomic_store(ob + (size_t)s*1024 + dir*512 + unit,
                         __float_as_uint(h), __ATOMIC_RELAXED, __HIP_MEMORY_SCOPE_AGENT);
    }
  }
}

// ---------------- row softmax, in place ----------------
__global__ __launch_bounds__(256) void k_softmax(float* __restrict__ P){
  __shared__ float redm[4], reds[4];
  const int i = blockIdx.x, tid = threadIdx.x;
  float4 v = *(float4*)&P[(size_t)i*1024 + tid*4];
  float m = fmaxf(fmaxf(v.x,v.y), fmaxf(v.z,v.w));
  #pragma unroll
  for (int o=32;o;o>>=1) m = fmaxf(m, __shfl_xor(m,o));
  if ((tid&63)==0) redm[tid>>6] = m;
  __syncthreads();
  m = fmaxf(fmaxf(redm[0],redm[1]), fmaxf(redm[2],redm[3]));
  v.x = expf(v.x-m); v.y = expf(v.y-m); v.z = expf(v.z-m); v.w = expf(v.w-m);
  float su = v.x+v.y+v.z+v.w;
  #pragma unroll
  for (int o=32;o;o>>=1) su += __shfl_xor(su,o);
  if ((tid&63)==0) reds[tid>>6] = su;
  __syncthreads();
  su = reds[0]+reds[1]+reds[2]+reds[3];
  float inv = 1.f/su;
  v.x*=inv; v.y*=inv; v.z*=inv; v.w*=inv;
  *(float4*)&P[(size_t)i*1024 + tid*4] = v;
}

extern "C" void kernel_launch(void* const* d_in, const int* in_sizes, int n_in,
                              void* d_out, int out_size, void* d_ws, size_t ws_size,
                              hipStream_t stream)
{
  const int*   x    = (const int*)d_in[0];
  const int*   xp   = (const int*)d_in[1];
  const float* we   = (const float*)d_in[2];
  const float* pe   = (const float*)d_in[3];
  const float* Wih  = (const float*)d_in[4];   // [2][2][2048][1024]
  const float* Whh  = (const float*)d_in[5];   // [2][2][2048][512]
  const float* bl   = (const float*)d_in[6];   // [2][2][2048]
  const float* Wh   = (const float*)d_in[7];
  const float* bh   = (const float*)d_in[8];
  const float* Wd   = (const float*)d_in[9];
  const float* bd   = (const float*)d_in[10];
  const float* Wbi  = (const float*)d_in[11];
  const float* bbi  = (const float*)d_in[12];
  float* outp = (float*)d_out;

  // workspace layout (28 MB), with reuse after the scans:
  char* ws = (char*)d_ws;
  float* X0   = (float*)(ws);                  // [0,4M)   embeddings
  float* pre  = (float*)(ws + ((size_t)4<<20));// [4M,20M) input projections
  float* out0 = (float*)(ws + ((size_t)20<<20));// [20M,24M)
  float* out1 = (float*)(ws + ((size_t)24<<20));// [24M,28M)
  float* head = (float*)(ws);                  // reuse [0,4M)
  float* dep  = (float*)(ws + ((size_t)4<<20));// reuse [4M,8M)
  float* Ubuf = (float*)(ws + ((size_t)8<<20));// reuse [8M,12M)

  // sentinel-init the scan outputs (data-as-flag scheme), every launch
  hipMemsetAsync(out0, 0x7F, (size_t)4<<20, stream);
  hipMemsetAsync(out1, 0x7F, (size_t)4<<20, stream);

  dim3 blk(256);
  k_embed<<<1024, blk, 0, stream>>>(x, xp, we, pe, X0);

  // layer 0: pre = X0 * Wih[0]^T + b[0]  (both dirs stacked: N=4096)
  k_gemm_abT<<<dim3(32,8), blk, 0, stream>>>(X0, Wih, pre, 1024, 4096, 1024, bl, nullptr);
  k_lstm_scan<<<256, dim3(128), 0, stream>>>(pre, Whh, out0);

  // layer 1
  k_gemm_abT<<<dim3(32,8), blk, 0, stream>>>(out0, Wih + (size_t)4096*1024, pre,
                                             1024, 4096, 1024, bl + 4096, nullptr);
  k_lstm_scan<<<256, dim3(128), 0, stream>>>(pre, Whh + (size_t)2*2048*512, out1);

  // biaffine: head = out1*Wh^T+bh ; dep = out1*Wd^T+bd ; U = dep*Wbi^T ; scores = head*U^T + bbi
  k_gemm_abT<<<dim3(8,8), blk, 0, stream>>>(out1, Wh, head, 1024, 1024, 1024, bh, nullptr);
  k_gemm_abT<<<dim3(8,8), blk, 0, stream>>>(out1, Wd, dep,  1024, 1024, 1024, bd, nullptr);
  k_gemm_abT<<<dim3(8,8), blk, 0, stream>>>(dep,  Wbi, Ubuf,1024, 1024, 1024, nullptr, nullptr);
  k_gemm_abT<<<dim3(8,8), blk, 0, stream>>>(head, Ubuf, outp,1024, 1024, 1024, nullptr, bbi);

  k_softmax<<<1024, blk, 0, stream>>>(outp);
}

// Round 5
// 7142.667 us; speedup vs baseline: 1.1396x; 1.1396x over previous
//
#include <hip/hip_runtime.h>
#include <hip/hip_bf16.h>
#include <cstdint>

#define SENTW 0x7F7F7F7Fu   // float ~3.39e38; |h|<1 so never produced by LSTM

// fast activations: v_exp_f32 (2^x) + v_rcp_f32, ~1-2 ulp each — on the
// serial recurrence chain, replacing ~25-instr libm expf/tanhf sequences.
__device__ __forceinline__ float fexp(float x){
  return __builtin_amdgcn_exp2f(x * 1.44269504088896341f);
}
__device__ __forceinline__ float sigf(float x){
  return __builtin_amdgcn_rcpf(1.f + fexp(-x));
}
__device__ __forceinline__ float tanh_fast(float x){
  return 1.f - 2.f*__builtin_amdgcn_rcpf(fexp(2.f*x) + 1.f);
}

// ---------------- embedding: X[s] = concat(word_emb[x[s]], pos_emb[x_pos[s]]) ----------------
__global__ __launch_bounds__(256) void k_embed(
    const int* __restrict__ x, const int* __restrict__ xp,
    const float* __restrict__ we, const float* __restrict__ pe,
    float* __restrict__ X)
{
  const int s = blockIdx.x, t = threadIdx.x;
  float4* xr = (float4*)(X + (size_t)s*1024);
  if (t < 224){                                  // 224*4 = 896 word dims
    const float4* wr = (const float4*)(we + (size_t)x[s]*896);
    xr[t] = wr[t];
  } else {                                       // 32*4 = 128 pos dims
    const float4* pr = (const float4*)(pe + (size_t)xp[s]*128);
    xr[t] = pr[t-224];
  }
}

// ---------------- fp32 GEMM: C[M,N] = A[M,K] * B[N,K]^T + bias[n] + (*cadd) ----------------
// BM=BN=128, BK=16, 256 threads, 8x8 micro-tile.
__global__ __launch_bounds__(256,2) void k_gemm_abT(
    const float* __restrict__ A, const float* __restrict__ B, float* __restrict__ C,
    int M, int N, int K,
    const float* __restrict__ bias, const float* __restrict__ cadd)
{
  __shared__ float As[16][132];
  __shared__ float Bs[16][132];
  const int tid = threadIdx.x;
  const int m0 = blockIdx.y*128, n0 = blockIdx.x*128;
  const int r  = tid>>1, cq = tid&1;       // loader mapping: row r, k-half cq
  const int ty = tid>>4, tx = tid&15;      // compute mapping

  float acc[8][8];
  #pragma unroll
  for (int i=0;i<8;i++)
    #pragma unroll
    for (int j=0;j<8;j++) acc[i][j]=0.f;

  for (int k0=0;k0<K;k0+=16){
    const float* ap = A + (size_t)(m0+r)*K + k0 + cq*8;
    const float* bp = B + (size_t)(n0+r)*K + k0 + cq*8;
    float4 a0 = *(const float4*)ap;
    float4 a1 = *(const float4*)(ap+4);
    float4 b0 = *(const float4*)bp;
    float4 b1 = *(const float4*)(bp+4);
    __syncthreads();   // previous iteration's LDS reads done
    As[cq*8+0][r]=a0.x; As[cq*8+1][r]=a0.y; As[cq*8+2][r]=a0.z; As[cq*8+3][r]=a0.w;
    As[cq*8+4][r]=a1.x; As[cq*8+5][r]=a1.y; As[cq*8+6][r]=a1.z; As[cq*8+7][r]=a1.w;
    Bs[cq*8+0][r]=b0.x; Bs[cq*8+1][r]=b0.y; Bs[cq*8+2][r]=b0.z; Bs[cq*8+3][r]=b0.w;
    Bs[cq*8+4][r]=b1.x; Bs[cq*8+5][r]=b1.y; Bs[cq*8+6][r]=b1.z; Bs[cq*8+7][r]=b1.w;
    __syncthreads();
    #pragma unroll
    for (int k=0;k<16;k++){
      float4 av0 = *(const float4*)&As[k][ty*8];
      float4 av1 = *(const float4*)&As[k][ty*8+4];
      float4 bv0 = *(const float4*)&Bs[k][tx*8];
      float4 bv1 = *(const float4*)&Bs[k][tx*8+4];
      float a[8]={av0.x,av0.y,av0.z,av0.w,av1.x,av1.y,av1.z,av1.w};
      float b[8]={bv0.x,bv0.y,bv0.z,bv0.w,bv1.x,bv1.y,bv1.z,bv1.w};
      #pragma unroll
      for (int i=0;i<8;i++)
        #pragma unroll
        for (int j=0;j<8;j++)
          acc[i][j] = fmaf(a[i],b[j],acc[i][j]);
    }
  }

  float cb = cadd ? *cadd : 0.f;
  float bv[8];
  if (bias){
    float4 t0 = *(const float4*)&bias[n0+tx*8];
    float4 t1 = *(const float4*)&bias[n0+tx*8+4];
    bv[0]=t0.x; bv[1]=t0.y; bv[2]=t0.z; bv[3]=t0.w;
    bv[4]=t1.x; bv[5]=t1.y; bv[6]=t1.z; bv[7]=t1.w;
  } else {
    #pragma unroll
    for (int j=0;j<8;j++) bv[j]=0.f;
  }
  #pragma unroll
  for (int i=0;i<8;i++){
    float* cp = C + (size_t)(m0+ty*8+i)*N + n0+tx*8;
    float4 o0, o1;
    o0.x=acc[i][0]+bv[0]+cb; o0.y=acc[i][1]+bv[1]+cb;
    o0.z=acc[i][2]+bv[2]+cb; o0.w=acc[i][3]+bv[3]+cb;
    o1.x=acc[i][4]+bv[4]+cb; o1.y=acc[i][5]+bv[5]+cb;
    o1.z=acc[i][6]+bv[6]+cb; o1.w=acc[i][7]+bv[7]+cb;
    *(float4*)cp = o0; *(float4*)(cp+4) = o1;
  }
}

// ---------------- LSTM scan, one layer, both directions ----------------
// R2 topology (best measured): 128 WGs x 256 thr; WG owns 8 units (32 rows,
// weights register-resident). Data-as-flag sentinel sync. R4 changes:
// fast v_exp activations, dual-outstanding poll (sample interval ~RTT/2),
// paired u64 producer stores (4 msgs/WG instead of 8).
__global__ __launch_bounds__(256,1) void k_lstm_scan(
    const float* __restrict__ pre,   // [1024][4096]: dir*2048 + gate*512 + unit
    const float* __restrict__ Whh,   // [2][2048][512] (this layer)
    float* __restrict__ out)         // [1024][1024]; fwd cols 0..511, bwd 512..1023
{
  const int wg  = blockIdx.x;
  const int dir = wg >> 6;
  const int w   = wg & 63;
  const int tid = threadIdx.x;
  const int kc  = tid & 7;         // k-chunk (64 floats)
  const int rl  = tid >> 3;        // local row 0..31
  const int gate= rl & 3;          // i,f,g,o
  const int ul  = rl >> 2;         // local unit 0..7
  const int unit= w*8 + ul;
  const int grow= gate*512 + unit; // row in W_hh

  // swizzled LDS: logical h[i] at slot (i>>6)*68 + (i&63);
  // chunk bases hit banks 0,4,..,28 -> conflict-free b128 reads (R2-verified).
  __shared__ float hsh[2][544];
  const int wslot = (tid>>5)*68 + ((2*tid)&63);   // write slot for h[2*tid]

  // register-resident weights: this thread's 64 elements of its row
  float wreg[64];
  {
    const float* wp = Whh + ((size_t)dir*2048 + grow)*512 + kc*64;
    #pragma unroll
    for (int j=0;j<16;j++){
      float4 q = *(const float4*)(wp + 4*j);
      wreg[4*j+0]=q.x; wreg[4*j+1]=q.y; wreg[4*j+2]=q.z; wreg[4*j+3]=q.w;
    }
  }

  unsigned* ob = (unsigned*)out;
  const float* prebase = pre + (size_t)dir*2048 + grow;
  float c = 0.f;
  const int base = (tid & 32);     // wave-lane base of this unit's gate group

  for (int t=0;t<1024;t++){
    const int s  = dir ? (1023 - t) : t;
    const int sp = dir ? (s + 1) : (s - 1);

    // prefetch input-projection value (independent of h -> issues before poll)
    float preval = 0.f;
    if (kc==0) preval = prebase[(size_t)s*4096];

    float accv = 0.f;
    if (t > 0){
      // poll this thread's u64 of h[sp]; keep 2 loads in flight so the
      // sampling interval is ~RTT/2 (value is write-once: stale-ready == ready)
      unsigned long long* hp64 =
          (unsigned long long*)(ob + (size_t)sp*1024 + dir*512 + 2*tid);
      unsigned long long va = __hip_atomic_load(hp64, __ATOMIC_RELAXED, __HIP_MEMORY_SCOPE_AGENT);
      unsigned long long vb = __hip_atomic_load(hp64, __ATOMIC_RELAXED, __HIP_MEMORY_SCOPE_AGENT);
      for(;;){
        if ((unsigned)va != SENTW && (unsigned)(va>>32) != SENTW) break;
        va = vb;
        vb = __hip_atomic_load(hp64, __ATOMIC_RELAXED, __HIP_MEMORY_SCOPE_AGENT);
      }
      float* hb = hsh[t & 1];
      hb[wslot]   = __uint_as_float((unsigned)va);
      hb[wslot+1] = __uint_as_float((unsigned)(va>>32));
      __syncthreads();               // LDS copy complete (also fences prev-buf reuse)

      const float* hv = hb + kc*68;
      float p0=0.f,p1=0.f,p2=0.f,p3=0.f;
      #pragma unroll
      for (int j=0;j<16;j++){
        float4 q = *(const float4*)(hv + 4*j);
        p0 = fmaf(wreg[4*j+0], q.x, p0);
        p1 = fmaf(wreg[4*j+1], q.y, p1);
        p2 = fmaf(wreg[4*j+2], q.z, p2);
        p3 = fmaf(wreg[4*j+3], q.w, p3);
      }
      accv = (p0+p1)+(p2+p3);
      accv += __shfl_xor(accv, 1);
      accv += __shfl_xor(accv, 2);
      accv += __shfl_xor(accv, 4);   // lanes with kc==0 hold the full dot
    }
    // per-gate activation on the head lane of each row (parallel across rows)
    float act = 0.f;
    if (kc==0){
      float g = accv + preval;
      act = (gate==2) ? tanh_fast(g) : sigf(g);
    }
    // gather the 4 activated gates of this unit (lanes base+{0,8,16,24})
    float ai = __shfl(act, base+0);
    float af = __shfl(act, base+8);
    float ag = __shfl(act, base+16);
    float ao = __shfl(act, base+24);
    float h = 0.f;
    if ((tid&31)==0){                // head lanes 0,32 of each wave (units 2W, 2W+1)
      c = af*c + ai*ag;
      h = ao*tanh_fast(c);
    }
    // pack the wave's two units into one u64 store (lane 0 of each wave)
    float h2 = __shfl(h, 32);        // partner unit's h (lane 32)
    if ((tid&63)==0){
      unsigned long long pv =
          ((unsigned long long)__float_as_uint(h2) << 32) | __float_as_uint(h);
      unsigned long long* dst =
          (unsigned long long*)(ob + (size_t)s*1024 + dir*512) + (w*4 + (tid>>6));
      __hip_atomic_store(dst, pv, __ATOMIC_RELAXED, __HIP_MEMORY_SCOPE_AGENT);
    }
  }
}

// ---------------- row softmax, in place ----------------
__global__ __launch_bounds__(256) void k_softmax(float* __restrict__ P){
  __shared__ float redm[4], reds[4];
  const int i = blockIdx.x, tid = threadIdx.x;
  float4 v = *(float4*)&P[(size_t)i*1024 + tid*4];
  float m = fmaxf(fmaxf(v.x,v.y), fmaxf(v.z,v.w));
  #pragma unroll
  for (int o=32;o;o>>=1) m = fmaxf(m, __shfl_xor(m,o));
  if ((tid&63)==0) redm[tid>>6] = m;
  __syncthreads();
  m = fmaxf(fmaxf(redm[0],redm[1]), fmaxf(redm[2],redm[3]));
  v.x = expf(v.x-m); v.y = expf(v.y-m); v.z = expf(v.z-m); v.w = expf(v.w-m);
  float su = v.x+v.y+v.z+v.w;
  #pragma unroll
  for (int o=32;o;o>>=1) su += __shfl_xor(su,o);
  if ((tid&63)==0) reds[tid>>6] = su;
  __syncthreads();
  su = reds[0]+reds[1]+reds[2]+reds[3];
  float inv = 1.f/su;
  v.x*=inv; v.y*=inv; v.z*=inv; v.w*=inv;
  *(float4*)&P[(size_t)i*1024 + tid*4] = v;
}

extern "C" void kernel_launch(void* const* d_in, const int* in_sizes, int n_in,
                              void* d_out, int out_size, void* d_ws, size_t ws_size,
                              hipStream_t stream)
{
  const int*   x    = (const int*)d_in[0];
  const int*   xp   = (const int*)d_in[1];
  const float* we   = (const float*)d_in[2];
  const float* pe   = (const float*)d_in[3];
  const float* Wih  = (const float*)d_in[4];   // [2][2][2048][1024]
  const float* Whh  = (const float*)d_in[5];   // [2][2][2048][512]
  const float* bl   = (const float*)d_in[6];   // [2][2][2048]
  const float* Wh   = (const float*)d_in[7];
  const float* bh   = (const float*)d_in[8];
  const float* Wd   = (const float*)d_in[9];
  const float* bd   = (const float*)d_in[10];
  const float* Wbi  = (const float*)d_in[11];
  const float* bbi  = (const float*)d_in[12];
  float* outp = (float*)d_out;

  // workspace layout (28 MB), with reuse after the scans:
  char* ws = (char*)d_ws;
  float* X0   = (float*)(ws);                  // [0,4M)   embeddings
  float* pre  = (float*)(ws + ((size_t)4<<20));// [4M,20M) input projections
  float* out0 = (float*)(ws + ((size_t)20<<20));// [20M,24M)
  float* out1 = (float*)(ws + ((size_t)24<<20));// [24M,28M)
  float* head = (float*)(ws);                  // reuse [0,4M)
  float* dep  = (float*)(ws + ((size_t)4<<20));// reuse [4M,8M)
  float* Ubuf = (float*)(ws + ((size_t)8<<20));// reuse [8M,12M)

  // sentinel-init the scan outputs (one contiguous 8MB memset)
  hipMemsetAsync(out0, 0x7F, (size_t)8<<20, stream);

  dim3 blk(256);
  k_embed<<<1024, blk, 0, stream>>>(x, xp, we, pe, X0);

  // layer 0: pre = X0 * Wih[0]^T + b[0]  (both dirs stacked: N=4096)
  k_gemm_abT<<<dim3(32,8), blk, 0, stream>>>(X0, Wih, pre, 1024, 4096, 1024, bl, nullptr);
  k_lstm_scan<<<128, blk, 0, stream>>>(pre, Whh, out0);

  // layer 1
  k_gemm_abT<<<dim3(32,8), blk, 0, stream>>>(out0, Wih + (size_t)4096*1024, pre,
                                             1024, 4096, 1024, bl + 4096, nullptr);
  k_lstm_scan<<<128, blk, 0, stream>>>(pre, Whh + (size_t)2*2048*512, out1);

  // biaffine: head = out1*Wh^T+bh ; dep = out1*Wd^T+bd ; U = dep*Wbi^T ; scores = head*U^T + bbi
  k_gemm_abT<<<dim3(8,8), blk, 0, stream>>>(out1, Wh, head, 1024, 1024, 1024, bh, nullptr);
  k_gemm_abT<<<dim3(8,8), blk, 0, stream>>>(out1, Wd, dep,  1024, 1024, 1024, bd, nullptr);
  k_gemm_abT<<<dim3(8,8), blk, 0, stream>>>(dep,  Wbi, Ubuf,1024, 1024, 1024, nullptr, nullptr);
  k_gemm_abT<<<dim3(8,8), blk, 0, stream>>>(head, Ubuf, outp,1024, 1024, 1024, nullptr, bbi);

  k_softmax<<<1024, blk, 0, stream>>>(outp);
}

// Round 6
// 6496.416 us; speedup vs baseline: 1.2529x; 1.0995x over previous
//
#include <hip/hip_runtime.h>
#include <hip/hip_bf16.h>
#include <cstdint>

#define SENTW 0x7F7F7F7Fu   // float ~3.39e38; |h|<1 so never produced by LSTM

// fast activations: v_exp_f32 (2^x) + v_rcp_f32, ~1-2 ulp each — on the
// serial recurrence chain, replacing ~25-instr libm expf/tanhf sequences.
__device__ __forceinline__ float fexp(float x){
  return __builtin_amdgcn_exp2f(x * 1.44269504088896341f);
}
__device__ __forceinline__ float sigf(float x){
  return __builtin_amdgcn_rcpf(1.f + fexp(-x));
}
__device__ __forceinline__ float tanh_fast(float x){
  return 1.f - 2.f*__builtin_amdgcn_rcpf(fexp(2.f*x) + 1.f);
}

// ---------------- embedding: X[s] = concat(word_emb[x[s]], pos_emb[x_pos[s]]) ----------------
__global__ __launch_bounds__(256) void k_embed(
    const int* __restrict__ x, const int* __restrict__ xp,
    const float* __restrict__ we, const float* __restrict__ pe,
    float* __restrict__ X)
{
  const int s = blockIdx.x, t = threadIdx.x;
  float4* xr = (float4*)(X + (size_t)s*1024);
  if (t < 224){                                  // 224*4 = 896 word dims
    const float4* wr = (const float4*)(we + (size_t)x[s]*896);
    xr[t] = wr[t];
  } else {                                       // 32*4 = 128 pos dims
    const float4* pr = (const float4*)(pe + (size_t)xp[s]*128);
    xr[t] = pr[t-224];
  }
}

// ---------------- fp32 GEMM: C[M,N] = A[M,K] * B[N,K]^T + bias[n] + (*cadd) ----------------
// BM=BN=128, BK=16, 256 threads, 8x8 micro-tile.
__global__ __launch_bounds__(256,2) void k_gemm_abT(
    const float* __restrict__ A, const float* __restrict__ B, float* __restrict__ C,
    int M, int N, int K,
    const float* __restrict__ bias, const float* __restrict__ cadd)
{
  __shared__ float As[16][132];
  __shared__ float Bs[16][132];
  const int tid = threadIdx.x;
  const int m0 = blockIdx.y*128, n0 = blockIdx.x*128;
  const int r  = tid>>1, cq = tid&1;       // loader mapping: row r, k-half cq
  const int ty = tid>>4, tx = tid&15;      // compute mapping

  float acc[8][8];
  #pragma unroll
  for (int i=0;i<8;i++)
    #pragma unroll
    for (int j=0;j<8;j++) acc[i][j]=0.f;

  for (int k0=0;k0<K;k0+=16){
    const float* ap = A + (size_t)(m0+r)*K + k0 + cq*8;
    const float* bp = B + (size_t)(n0+r)*K + k0 + cq*8;
    float4 a0 = *(const float4*)ap;
    float4 a1 = *(const float4*)(ap+4);
    float4 b0 = *(const float4*)bp;
    float4 b1 = *(const float4*)(bp+4);
    __syncthreads();   // previous iteration's LDS reads done
    As[cq*8+0][r]=a0.x; As[cq*8+1][r]=a0.y; As[cq*8+2][r]=a0.z; As[cq*8+3][r]=a0.w;
    As[cq*8+4][r]=a1.x; As[cq*8+5][r]=a1.y; As[cq*8+6][r]=a1.z; As[cq*8+7][r]=a1.w;
    Bs[cq*8+0][r]=b0.x; Bs[cq*8+1][r]=b0.y; Bs[cq*8+2][r]=b0.z; Bs[cq*8+3][r]=b0.w;
    Bs[cq*8+4][r]=b1.x; Bs[cq*8+5][r]=b1.y; Bs[cq*8+6][r]=b1.z; Bs[cq*8+7][r]=b1.w;
    __syncthreads();
    #pragma unroll
    for (int k=0;k<16;k++){
      float4 av0 = *(const float4*)&As[k][ty*8];
      float4 av1 = *(const float4*)&As[k][ty*8+4];
      float4 bv0 = *(const float4*)&Bs[k][tx*8];
      float4 bv1 = *(const float4*)&Bs[k][tx*8+4];
      float a[8]={av0.x,av0.y,av0.z,av0.w,av1.x,av1.y,av1.z,av1.w};
      float b[8]={bv0.x,bv0.y,bv0.z,bv0.w,bv1.x,bv1.y,bv1.z,bv1.w};
      #pragma unroll
      for (int i=0;i<8;i++)
        #pragma unroll
        for (int j=0;j<8;j++)
          acc[i][j] = fmaf(a[i],b[j],acc[i][j]);
    }
  }

  float cb = cadd ? *cadd : 0.f;
  float bv[8];
  if (bias){
    float4 t0 = *(const float4*)&bias[n0+tx*8];
    float4 t1 = *(const float4*)&bias[n0+tx*8+4];
    bv[0]=t0.x; bv[1]=t0.y; bv[2]=t0.z; bv[3]=t0.w;
    bv[4]=t1.x; bv[5]=t1.y; bv[6]=t1.z; bv[7]=t1.w;
  } else {
    #pragma unroll
    for (int j=0;j<8;j++) bv[j]=0.f;
  }
  #pragma unroll
  for (int i=0;i<8;i++){
    float* cp = C + (size_t)(m0+ty*8+i)*N + n0+tx*8;
    float4 o0, o1;
    o0.x=acc[i][0]+bv[0]+cb; o0.y=acc[i][1]+bv[1]+cb;
    o0.z=acc[i][2]+bv[2]+cb; o0.w=acc[i][3]+bv[3]+cb;
    o1.x=acc[i][4]+bv[4]+cb; o1.y=acc[i][5]+bv[5]+cb;
    o1.z=acc[i][6]+bv[6]+cb; o1.w=acc[i][7]+bv[7]+cb;
    *(float4*)cp = o0; *(float4*)(cp+4) = o1;
  }
}

// ---- merged head/dep GEMM: one launch, n<1024 -> head(Wh,bh), else dep(Wd,bd) ----
__global__ __launch_bounds__(256,2) void k_gemm_hd(
    const float* __restrict__ A,
    const float* __restrict__ Wh, const float* __restrict__ bh, float* __restrict__ Chead,
    const float* __restrict__ Wd, const float* __restrict__ bd, float* __restrict__ Cdep)
{
  __shared__ float As[16][132];
  __shared__ float Bs[16][132];
  const int tid = threadIdx.x;
  const int m0 = blockIdx.y*128;
  const int half = blockIdx.x >> 3;            // 0: head, 1: dep
  const int n0 = (blockIdx.x & 7)*128;
  const float* B    = half ? Wd : Wh;
  const float* bias = half ? bd : bh;
  float*       C    = half ? Cdep : Chead;
  const int r  = tid>>1, cq = tid&1;
  const int ty = tid>>4, tx = tid&15;

  float acc[8][8];
  #pragma unroll
  for (int i=0;i<8;i++)
    #pragma unroll
    for (int j=0;j<8;j++) acc[i][j]=0.f;

  for (int k0=0;k0<1024;k0+=16){
    const float* ap = A + (size_t)(m0+r)*1024 + k0 + cq*8;
    const float* bp = B + (size_t)(n0+r)*1024 + k0 + cq*8;
    float4 a0 = *(const float4*)ap;
    float4 a1 = *(const float4*)(ap+4);
    float4 b0 = *(const float4*)bp;
    float4 b1 = *(const float4*)(bp+4);
    __syncthreads();
    As[cq*8+0][r]=a0.x; As[cq*8+1][r]=a0.y; As[cq*8+2][r]=a0.z; As[cq*8+3][r]=a0.w;
    As[cq*8+4][r]=a1.x; As[cq*8+5][r]=a1.y; As[cq*8+6][r]=a1.z; As[cq*8+7][r]=a1.w;
    Bs[cq*8+0][r]=b0.x; Bs[cq*8+1][r]=b0.y; Bs[cq*8+2][r]=b0.z; Bs[cq*8+3][r]=b0.w;
    Bs[cq*8+4][r]=b1.x; Bs[cq*8+5][r]=b1.y; Bs[cq*8+6][r]=b1.z; Bs[cq*8+7][r]=b1.w;
    __syncthreads();
    #pragma unroll
    for (int k=0;k<16;k++){
      float4 av0 = *(const float4*)&As[k][ty*8];
      float4 av1 = *(const float4*)&As[k][ty*8+4];
      float4 bv0 = *(const float4*)&Bs[k][tx*8];
      float4 bv1 = *(const float4*)&Bs[k][tx*8+4];
      float a[8]={av0.x,av0.y,av0.z,av0.w,av1.x,av1.y,av1.z,av1.w};
      float b[8]={bv0.x,bv0.y,bv0.z,bv0.w,bv1.x,bv1.y,bv1.z,bv1.w};
      #pragma unroll
      for (int i=0;i<8;i++)
        #pragma unroll
        for (int j=0;j<8;j++)
          acc[i][j] = fmaf(a[i],b[j],acc[i][j]);
    }
  }

  float4 t0 = *(const float4*)&bias[n0+tx*8];
  float4 t1 = *(const float4*)&bias[n0+tx*8+4];
  float bv[8] = {t0.x,t0.y,t0.z,t0.w,t1.x,t1.y,t1.z,t1.w};
  #pragma unroll
  for (int i=0;i<8;i++){
    float* cp = C + (size_t)(m0+ty*8+i)*1024 + n0+tx*8;
    float4 o0, o1;
    o0.x=acc[i][0]+bv[0]; o0.y=acc[i][1]+bv[1];
    o0.z=acc[i][2]+bv[2]; o0.w=acc[i][3]+bv[3];
    o1.x=acc[i][4]+bv[4]; o1.y=acc[i][5]+bv[5];
    o1.z=acc[i][6]+bv[6]; o1.w=acc[i][7]+bv[7];
    *(float4*)cp = o0; *(float4*)(cp+4) = o1;
  }
}

// ---------------- LSTM scan, one layer, both directions ----------------
// R2 topology (best measured): 128 WGs x 256 thr; WG owns 8 units (32 rows,
// weights register-resident). Data-as-flag sentinel sync; single u64 poll per
// thread; swizzled LDS redistribute (conflict-free, R2-verified). R5 change:
// producer h store is a global_atomic_swap RMW — executes at the memory-side
// cache, so the value is AT the coherence point when serviced (tests the
// store-visibility-latency hypothesis). Fast v_exp activations kept from R4.
__global__ __launch_bounds__(256,1) void k_lstm_scan(
    const float* __restrict__ pre,   // [1024][4096]: dir*2048 + gate*512 + unit
    const float* __restrict__ Whh,   // [2][2048][512] (this layer)
    float* __restrict__ out)         // [1024][1024]; fwd cols 0..511, bwd 512..1023
{
  const int wg  = blockIdx.x;
  const int dir = wg >> 6;
  const int w   = wg & 63;
  const int tid = threadIdx.x;
  const int kc  = tid & 7;         // k-chunk (64 floats)
  const int rl  = tid >> 3;        // local row 0..31
  const int gate= rl & 3;          // i,f,g,o
  const int ul  = rl >> 2;         // local unit 0..7
  const int unit= w*8 + ul;
  const int grow= gate*512 + unit; // row in W_hh

  // swizzled LDS: logical h[i] at slot (i>>6)*68 + (i&63);
  // chunk bases hit banks 0,4,..,28 -> conflict-free b128 reads (R2-verified).
  __shared__ float hsh[2][544];
  const int wslot = (tid>>5)*68 + ((2*tid)&63);   // write slot for h[2*tid]

  // register-resident weights: this thread's 64 elements of its row
  float wreg[64];
  {
    const float* wp = Whh + ((size_t)dir*2048 + grow)*512 + kc*64;
    #pragma unroll
    for (int j=0;j<16;j++){
      float4 q = *(const float4*)(wp + 4*j);
      wreg[4*j+0]=q.x; wreg[4*j+1]=q.y; wreg[4*j+2]=q.z; wreg[4*j+3]=q.w;
    }
  }

  unsigned* ob = (unsigned*)out;
  const float* prebase = pre + (size_t)dir*2048 + grow;
  float c = 0.f;
  const int base = (tid & 32);     // wave-lane base of this unit's gate group

  for (int t=0;t<1024;t++){
    const int s  = dir ? (1023 - t) : t;
    const int sp = dir ? (s + 1) : (s - 1);

    // prefetch input-projection value (independent of h -> issues before poll)
    float preval = 0.f;
    if (kc==0) preval = prebase[(size_t)s*4096];

    float accv = 0.f;
    if (t > 0){
      // poll ONLY this thread's 2 dwords of h[sp] via one 64-bit load
      unsigned long long* hp64 =
          (unsigned long long*)(ob + (size_t)sp*1024 + dir*512 + 2*tid);
      unsigned long long vv;
      for(;;){
        vv = __hip_atomic_load(hp64, __ATOMIC_RELAXED, __HIP_MEMORY_SCOPE_AGENT);
        if ((unsigned)vv != SENTW && (unsigned)(vv>>32) != SENTW) break;
      }
      float* hb = hsh[t & 1];
      hb[wslot]   = __uint_as_float((unsigned)vv);
      hb[wslot+1] = __uint_as_float((unsigned)(vv>>32));
      __syncthreads();               // LDS copy complete (also fences prev-buf reuse)

      const float* hv = hb + kc*68;
      float p0=0.f,p1=0.f,p2=0.f,p3=0.f;
      #pragma unroll
      for (int j=0;j<16;j++){
        float4 q = *(const float4*)(hv + 4*j);
        p0 = fmaf(wreg[4*j+0], q.x, p0);
        p1 = fmaf(wreg[4*j+1], q.y, p1);
        p2 = fmaf(wreg[4*j+2], q.z, p2);
        p3 = fmaf(wreg[4*j+3], q.w, p3);
      }
      accv = (p0+p1)+(p2+p3);
      accv += __shfl_xor(accv, 1);
      accv += __shfl_xor(accv, 2);
      accv += __shfl_xor(accv, 4);   // lanes with kc==0 hold the full dot
    }
    // per-gate activation on the head lane of each row (parallel across rows)
    float act = 0.f;
    if (kc==0){
      float g = accv + preval;
      act = (gate==2) ? tanh_fast(g) : sigf(g);
    }
    // gather the 4 activated gates of this unit (lanes base+{0,8,16,24})
    float ai = __shfl(act, base+0);
    float af = __shfl(act, base+8);
    float ag = __shfl(act, base+16);
    float ao = __shfl(act, base+24);
    if ((tid&31)==0){
      c = af*c + ai*ag;
      float h = ao*tanh_fast(c);
      // atomic swap RMW: executes at the memory-side cache -> promptly visible
      (void)__hip_atomic_exchange(ob + (size_t)s*1024 + dir*512 + unit,
                                  __float_as_uint(h),
                                  __ATOMIC_RELAXED, __HIP_MEMORY_SCOPE_AGENT);
    }
  }
}

// ---------------- row softmax, in place ----------------
__global__ __launch_bounds__(256) void k_softmax(float* __restrict__ P){
  __shared__ float redm[4], reds[4];
  const int i = blockIdx.x, tid = threadIdx.x;
  float4 v = *(float4*)&P[(size_t)i*1024 + tid*4];
  float m = fmaxf(fmaxf(v.x,v.y), fmaxf(v.z,v.w));
  #pragma unroll
  for (int o=32;o;o>>=1) m = fmaxf(m, __shfl_xor(m,o));
  if ((tid&63)==0) redm[tid>>6] = m;
  __syncthreads();
  m = fmaxf(fmaxf(redm[0],redm[1]), fmaxf(redm[2],redm[3]));
  v.x = expf(v.x-m); v.y = expf(v.y-m); v.z = expf(v.z-m); v.w = expf(v.w-m);
  float su = v.x+v.y+v.z+v.w;
  #pragma unroll
  for (int o=32;o;o>>=1) su += __shfl_xor(su,o);
  if ((tid&63)==0) reds[tid>>6] = su;
  __syncthreads();
  su = reds[0]+reds[1]+reds[2]+reds[3];
  float inv = 1.f/su;
  v.x*=inv; v.y*=inv; v.z*=inv; v.w*=inv;
  *(float4*)&P[(size_t)i*1024 + tid*4] = v;
}

extern "C" void kernel_launch(void* const* d_in, const int* in_sizes, int n_in,
                              void* d_out, int out_size, void* d_ws, size_t ws_size,
                              hipStream_t stream)
{
  const int*   x    = (const int*)d_in[0];
  const int*   xp   = (const int*)d_in[1];
  const float* we   = (const float*)d_in[2];
  const float* pe   = (const float*)d_in[3];
  const float* Wih  = (const float*)d_in[4];   // [2][2][2048][1024]
  const float* Whh  = (const float*)d_in[5];   // [2][2][2048][512]
  const float* bl   = (const float*)d_in[6];   // [2][2][2048]
  const float* Wh   = (const float*)d_in[7];
  const float* bh   = (const float*)d_in[8];
  const float* Wd   = (const float*)d_in[9];
  const float* bd   = (const float*)d_in[10];
  const float* Wbi  = (const float*)d_in[11];
  const float* bbi  = (const float*)d_in[12];
  float* outp = (float*)d_out;

  // workspace layout (28 MB), with reuse after the scans:
  char* ws = (char*)d_ws;
  float* X0   = (float*)(ws);                  // [0,4M)   embeddings
  float* pre  = (float*)(ws + ((size_t)4<<20));// [4M,20M) input projections
  float* out0 = (float*)(ws + ((size_t)20<<20));// [20M,24M)
  float* out1 = (float*)(ws + ((size_t)24<<20));// [24M,28M)
  float* head = (float*)(ws);                  // reuse [0,4M)
  float* dep  = (float*)(ws + ((size_t)4<<20));// reuse [4M,8M)
  float* Ubuf = (float*)(ws + ((size_t)8<<20));// reuse [8M,12M)

  // sentinel-init the scan outputs (one contiguous 8MB memset)
  hipMemsetAsync(out0, 0x7F, (size_t)8<<20, stream);

  dim3 blk(256);
  k_embed<<<1024, blk, 0, stream>>>(x, xp, we, pe, X0);

  // layer 0: pre = X0 * Wih[0]^T + b[0]  (both dirs stacked: N=4096)
  k_gemm_abT<<<dim3(32,8), blk, 0, stream>>>(X0, Wih, pre, 1024, 4096, 1024, bl, nullptr);
  k_lstm_scan<<<128, blk, 0, stream>>>(pre, Whh, out0);

  // layer 1
  k_gemm_abT<<<dim3(32,8), blk, 0, stream>>>(out0, Wih + (size_t)4096*1024, pre,
                                             1024, 4096, 1024, bl + 4096, nullptr);
  k_lstm_scan<<<128, blk, 0, stream>>>(pre, Whh + (size_t)2*2048*512, out1);

  // biaffine: head|dep merged; U = dep*Wbi^T ; scores = head*U^T + bbi
  k_gemm_hd <<<dim3(16,8), blk, 0, stream>>>(out1, Wh, bh, head, Wd, bd, dep);
  k_gemm_abT<<<dim3(8,8), blk, 0, stream>>>(dep,  Wbi, Ubuf,1024, 1024, 1024, nullptr, nullptr);
  k_gemm_abT<<<dim3(8,8), blk, 0, stream>>>(head, Ubuf, outp,1024, 1024, 1024, nullptr, bbi);

  k_softmax<<<1024, blk, 0, stream>>>(outp);
}

// Round 7
// 6410.876 us; speedup vs baseline: 1.2697x; 1.0133x over previous
//
#include <hip/hip_runtime.h>
#include <hip/hip_bf16.h>
#include <cstdint>

#define SENTW 0x7F7F7F7Fu   // float ~3.39e38; |h|<1 so never produced by LSTM

typedef unsigned uint4v __attribute__((ext_vector_type(4)));

// fast activations: v_exp_f32 (2^x) + v_rcp_f32, ~1-2 ulp each — on the
// serial recurrence chain, replacing ~25-instr libm expf/tanhf sequences.
__device__ __forceinline__ float fexp(float x){
  return __builtin_amdgcn_exp2f(x * 1.44269504088896341f);
}
__device__ __forceinline__ float sigf(float x){
  return __builtin_amdgcn_rcpf(1.f + fexp(-x));
}
__device__ __forceinline__ float tanh_fast(float x){
  return 1.f - 2.f*__builtin_amdgcn_rcpf(fexp(2.f*x) + 1.f);
}

// ---------------- embedding: X[s] = concat(word_emb[x[s]], pos_emb[x_pos[s]]) ----------------
__global__ __launch_bounds__(256) void k_embed(
    const int* __restrict__ x, const int* __restrict__ xp,
    const float* __restrict__ we, const float* __restrict__ pe,
    float* __restrict__ X)
{
  const int s = blockIdx.x, t = threadIdx.x;
  float4* xr = (float4*)(X + (size_t)s*1024);
  if (t < 224){                                  // 224*4 = 896 word dims
    const float4* wr = (const float4*)(we + (size_t)x[s]*896);
    xr[t] = wr[t];
  } else {                                       // 32*4 = 128 pos dims
    const float4* pr = (const float4*)(pe + (size_t)xp[s]*128);
    xr[t] = pr[t-224];
  }
}

// ---------------- fp32 GEMM: C[M,N] = A[M,K] * B[N,K]^T + bias[n] + (*cadd) ----------------
// BM=BN=128, BK=16, 256 threads, 8x8 micro-tile.
__global__ __launch_bounds__(256,2) void k_gemm_abT(
    const float* __restrict__ A, const float* __restrict__ B, float* __restrict__ C,
    int M, int N, int K,
    const float* __restrict__ bias, const float* __restrict__ cadd)
{
  __shared__ float As[16][132];
  __shared__ float Bs[16][132];
  const int tid = threadIdx.x;
  const int m0 = blockIdx.y*128, n0 = blockIdx.x*128;
  const int r  = tid>>1, cq = tid&1;       // loader mapping: row r, k-half cq
  const int ty = tid>>4, tx = tid&15;      // compute mapping

  float acc[8][8];
  #pragma unroll
  for (int i=0;i<8;i++)
    #pragma unroll
    for (int j=0;j<8;j++) acc[i][j]=0.f;

  for (int k0=0;k0<K;k0+=16){
    const float* ap = A + (size_t)(m0+r)*K + k0 + cq*8;
    const float* bp = B + (size_t)(n0+r)*K + k0 + cq*8;
    float4 a0 = *(const float4*)ap;
    float4 a1 = *(const float4*)(ap+4);
    float4 b0 = *(const float4*)bp;
    float4 b1 = *(const float4*)(bp+4);
    __syncthreads();   // previous iteration's LDS reads done
    As[cq*8+0][r]=a0.x; As[cq*8+1][r]=a0.y; As[cq*8+2][r]=a0.z; As[cq*8+3][r]=a0.w;
    As[cq*8+4][r]=a1.x; As[cq*8+5][r]=a1.y; As[cq*8+6][r]=a1.z; As[cq*8+7][r]=a1.w;
    Bs[cq*8+0][r]=b0.x; Bs[cq*8+1][r]=b0.y; Bs[cq*8+2][r]=b0.z; Bs[cq*8+3][r]=b0.w;
    Bs[cq*8+4][r]=b1.x; Bs[cq*8+5][r]=b1.y; Bs[cq*8+6][r]=b1.z; Bs[cq*8+7][r]=b1.w;
    __syncthreads();
    #pragma unroll
    for (int k=0;k<16;k++){
      float4 av0 = *(const float4*)&As[k][ty*8];
      float4 av1 = *(const float4*)&As[k][ty*8+4];
      float4 bv0 = *(const float4*)&Bs[k][tx*8];
      float4 bv1 = *(const float4*)&Bs[k][tx*8+4];
      float a[8]={av0.x,av0.y,av0.z,av0.w,av1.x,av1.y,av1.z,av1.w};
      float b[8]={bv0.x,bv0.y,bv0.z,bv0.w,bv1.x,bv1.y,bv1.z,bv1.w};
      #pragma unroll
      for (int i=0;i<8;i++)
        #pragma unroll
        for (int j=0;j<8;j++)
          acc[i][j] = fmaf(a[i],b[j],acc[i][j]);
    }
  }

  float cb = cadd ? *cadd : 0.f;
  float bv[8];
  if (bias){
    float4 t0 = *(const float4*)&bias[n0+tx*8];
    float4 t1 = *(const float4*)&bias[n0+tx*8+4];
    bv[0]=t0.x; bv[1]=t0.y; bv[2]=t0.z; bv[3]=t0.w;
    bv[4]=t1.x; bv[5]=t1.y; bv[6]=t1.z; bv[7]=t1.w;
  } else {
    #pragma unroll
    for (int j=0;j<8;j++) bv[j]=0.f;
  }
  #pragma unroll
  for (int i=0;i<8;i++){
    float* cp = C + (size_t)(m0+ty*8+i)*N + n0+tx*8;
    float4 o0, o1;
    o0.x=acc[i][0]+bv[0]+cb; o0.y=acc[i][1]+bv[1]+cb;
    o0.z=acc[i][2]+bv[2]+cb; o0.w=acc[i][3]+bv[3]+cb;
    o1.x=acc[i][4]+bv[4]+cb; o1.y=acc[i][5]+bv[5]+cb;
    o1.z=acc[i][6]+bv[6]+cb; o1.w=acc[i][7]+bv[7]+cb;
    *(float4*)cp = o0; *(float4*)(cp+4) = o1;
  }
}

// ---- merged head/dep GEMM: one launch, half 0 -> head(Wh,bh), half 1 -> dep(Wd,bd) ----
__global__ __launch_bounds__(256,2) void k_gemm_hd(
    const float* __restrict__ A,
    const float* __restrict__ Wh, const float* __restrict__ bh, float* __restrict__ Chead,
    const float* __restrict__ Wd, const float* __restrict__ bd, float* __restrict__ Cdep)
{
  __shared__ float As[16][132];
  __shared__ float Bs[16][132];
  const int tid = threadIdx.x;
  const int m0 = blockIdx.y*128;
  const int half = blockIdx.x >> 3;            // 0: head, 1: dep
  const int n0 = (blockIdx.x & 7)*128;
  const float* B    = half ? Wd : Wh;
  const float* bias = half ? bd : bh;
  float*       C    = half ? Cdep : Chead;
  const int r  = tid>>1, cq = tid&1;
  const int ty = tid>>4, tx = tid&15;

  float acc[8][8];
  #pragma unroll
  for (int i=0;i<8;i++)
    #pragma unroll
    for (int j=0;j<8;j++) acc[i][j]=0.f;

  for (int k0=0;k0<1024;k0+=16){
    const float* ap = A + (size_t)(m0+r)*1024 + k0 + cq*8;
    const float* bp = B + (size_t)(n0+r)*1024 + k0 + cq*8;
    float4 a0 = *(const float4*)ap;
    float4 a1 = *(const float4*)(ap+4);
    float4 b0 = *(const float4*)bp;
    float4 b1 = *(const float4*)(bp+4);
    __syncthreads();
    As[cq*8+0][r]=a0.x; As[cq*8+1][r]=a0.y; As[cq*8+2][r]=a0.z; As[cq*8+3][r]=a0.w;
    As[cq*8+4][r]=a1.x; As[cq*8+5][r]=a1.y; As[cq*8+6][r]=a1.z; As[cq*8+7][r]=a1.w;
    Bs[cq*8+0][r]=b0.x; Bs[cq*8+1][r]=b0.y; Bs[cq*8+2][r]=b0.z; Bs[cq*8+3][r]=b0.w;
    Bs[cq*8+4][r]=b1.x; Bs[cq*8+5][r]=b1.y; Bs[cq*8+6][r]=b1.z; Bs[cq*8+7][r]=b1.w;
    __syncthreads();
    #pragma unroll
    for (int k=0;k<16;k++){
      float4 av0 = *(const float4*)&As[k][ty*8];
      float4 av1 = *(const float4*)&As[k][ty*8+4];
      float4 bv0 = *(const float4*)&Bs[k][tx*8];
      float4 bv1 = *(const float4*)&Bs[k][tx*8+4];
      float a[8]={av0.x,av0.y,av0.z,av0.w,av1.x,av1.y,av1.z,av1.w};
      float b[8]={bv0.x,bv0.y,bv0.z,bv0.w,bv1.x,bv1.y,bv1.z,bv1.w};
      #pragma unroll
      for (int i=0;i<8;i++)
        #pragma unroll
        for (int j=0;j<8;j++)
          acc[i][j] = fmaf(a[i],b[j],acc[i][j]);
    }
  }

  float4 t0 = *(const float4*)&bias[n0+tx*8];
  float4 t1 = *(const float4*)&bias[n0+tx*8+4];
  float bv[8] = {t0.x,t0.y,t0.z,t0.w,t1.x,t1.y,t1.z,t1.w};
  #pragma unroll
  for (int i=0;i<8;i++){
    float* cp = C + (size_t)(m0+ty*8+i)*1024 + n0+tx*8;
    float4 o0, o1;
    o0.x=acc[i][0]+bv[0]; o0.y=acc[i][1]+bv[1];
    o0.z=acc[i][2]+bv[2]; o0.w=acc[i][3]+bv[3];
    o1.x=acc[i][4]+bv[4]; o1.y=acc[i][5]+bv[5];
    o1.z=acc[i][6]+bv[6]; o1.w=acc[i][7]+bv[7];
    *(float4*)cp = o0; *(float4*)(cp+4) = o1;
  }
}

// ---------------- LSTM scan, one layer, both directions ----------------
// R6 topology: 64 WGs x 512 thr; 32 WGs/dir, each owns 16 units (64 rows of
// W_hh register-resident: thread = row (tid>>3) x k-chunk (tid&7), 64 w/thr).
// Sync = data-as-flag sentinel. R6 changes vs R5 (contention hypothesis):
//  - wave 0 ONLY polls, via coherent global_load_dwordx4 sc0 sc1 (2/lane) with
//    s_sleep backoff -> 8x fewer poll requests per line at the LLC.
//  - producer publishes via paired u64 atomic swaps (8 msgs/WG, not 16).
__global__ __launch_bounds__(512,1) void k_lstm_scan(
    const float* __restrict__ pre,   // [1024][4096]: dir*2048 + gate*512 + unit
    const float* __restrict__ Whh,   // [2][2048][512] (this layer)
    float* __restrict__ out)         // [1024][1024]; fwd cols 0..511, bwd 512..1023
{
  const int wg  = blockIdx.x;
  const int dir = wg >> 5;
  const int w   = wg & 31;
  const int tid = threadIdx.x;
  const int kc  = tid & 7;         // k-chunk (64 floats)
  const int rl  = tid >> 3;        // local row 0..63
  const int gate= rl & 3;          // i,f,g,o
  const int ul  = rl >> 2;         // local unit 0..15
  const int unit= w*16 + ul;
  const int grow= gate*512 + unit; // row in W_hh

  // swizzled LDS: logical h[i] at slot (i>>6)*68 + (i&63);
  // chunk bases hit banks 0,4,..,28 -> conflict-free b128 reads (R2-verified).
  __shared__ float hsh[2][544];

  // register-resident weights: this thread's 64 elements of its row
  float wreg[64];
  {
    const float* wp = Whh + ((size_t)dir*2048 + grow)*512 + kc*64;
    #pragma unroll
    for (int j=0;j<16;j++){
      float4 q = *(const float4*)(wp + 4*j);
      wreg[4*j+0]=q.x; wreg[4*j+1]=q.y; wreg[4*j+2]=q.z; wreg[4*j+3]=q.w;
    }
  }

  unsigned* ob = (unsigned*)out;
  const float* prebase = pre + (size_t)dir*2048 + grow;
  float c = 0.f;
  const int base = (tid & 32);     // wave-lane base of this unit's gate group

  for (int t=0;t<1024;t++){
    const int s  = dir ? (1023 - t) : t;
    const int sp = dir ? (s + 1) : (s - 1);

    // prefetch input-projection value (independent of h -> issues before poll)
    float preval = 0.f;
    if (kc==0) preval = prebase[(size_t)s*4096];

    float accv = 0.f;
    if (t > 0){
      if (tid < 64){
        // wave-0 lane l polls h[sp][8l..8l+8) via two coherent 16B loads
        const unsigned* hp = ob + (size_t)sp*1024 + dir*512 + 8*tid;
        uint4v a, b;
        for(;;){
          asm volatile(
            "global_load_dwordx4 %0, %2, off sc0 sc1\n\t"
            "global_load_dwordx4 %1, %3, off sc0 sc1\n\t"
            "s_waitcnt vmcnt(0)"
            : "=&v"(a), "=&v"(b)
            : "v"(hp), "v"(hp+4)
            : "memory");
          unsigned ok = 1u;
          ok &= (unsigned)(a.x!=SENTW) & (unsigned)(a.y!=SENTW);
          ok &= (unsigned)(a.z!=SENTW) & (unsigned)(a.w!=SENTW);
          ok &= (unsigned)(b.x!=SENTW) & (unsigned)(b.y!=SENTW);
          ok &= (unsigned)(b.z!=SENTW) & (unsigned)(b.w!=SENTW);
          if (ok) break;
          __builtin_amdgcn_s_sleep(1);   // ~64cy backoff: cut LLC request rate
        }
        float* hb = hsh[t & 1];
        const int sb = (tid>>3)*68 + (tid&7)*8;  // swizzled slot of h[8*tid]
        hb[sb+0]=__uint_as_float(a.x); hb[sb+1]=__uint_as_float(a.y);
        hb[sb+2]=__uint_as_float(a.z); hb[sb+3]=__uint_as_float(a.w);
        hb[sb+4]=__uint_as_float(b.x); hb[sb+5]=__uint_as_float(b.y);
        hb[sb+6]=__uint_as_float(b.z); hb[sb+7]=__uint_as_float(b.w);
      }
      __syncthreads();               // staging complete (also fences prev-buf reuse)

      const float* hv = hsh[t & 1] + kc*68;
      float p0=0.f,p1=0.f,p2=0.f,p3=0.f;
      #pragma unroll
      for (int j=0;j<16;j++){
        float4 q = *(const float4*)(hv + 4*j);
        p0 = fmaf(wreg[4*j+0], q.x, p0);
        p1 = fmaf(wreg[4*j+1], q.y, p1);
        p2 = fmaf(wreg[4*j+2], q.z, p2);
        p3 = fmaf(wreg[4*j+3], q.w, p3);
      }
      accv = (p0+p1)+(p2+p3);
      accv += __shfl_xor(accv, 1);
      accv += __shfl_xor(accv, 2);
      accv += __shfl_xor(accv, 4);   // lanes with kc==0 hold the full dot
    }
    // per-gate activation on the head lane of each row (parallel across rows)
    float act = 0.f;
    if (kc==0){
      float g = accv + preval;
      act = (gate==2) ? tanh_fast(g) : sigf(g);
    }
    // gather the 4 activated gates of this unit (lanes base+{0,8,16,24})
    float ai = __shfl(act, base+0);
    float af = __shfl(act, base+8);
    float ag = __shfl(act, base+16);
    float ao = __shfl(act, base+24);
    float h = 0.f;
    if ((tid&31)==0){                // lanes 0,32 of each wave: units 2j, 2j+1
      c = af*c + ai*ag;
      h = ao*tanh_fast(c);
    }
    // pair the wave's two units into one u64 atomic swap (8 msgs/WG)
    float h2 = __shfl(h, 32);
    if ((tid&63)==0){
      unsigned long long pv =
          ((unsigned long long)__float_as_uint(h2) << 32) | __float_as_uint(h);
      unsigned long long* dst =
          (unsigned long long*)(ob + (size_t)s*1024 + dir*512) + (w*8 + (tid>>6));
      (void)__hip_atomic_exchange(dst, pv, __ATOMIC_RELAXED, __HIP_MEMORY_SCOPE_AGENT);
    }
  }
}

// ---------------- row softmax, in place ----------------
__global__ __launch_bounds__(256) void k_softmax(float* __restrict__ P){
  __shared__ float redm[4], reds[4];
  const int i = blockIdx.x, tid = threadIdx.x;
  float4 v = *(float4*)&P[(size_t)i*1024 + tid*4];
  float m = fmaxf(fmaxf(v.x,v.y), fmaxf(v.z,v.w));
  #pragma unroll
  for (int o=32;o;o>>=1) m = fmaxf(m, __shfl_xor(m,o));
  if ((tid&63)==0) redm[tid>>6] = m;
  __syncthreads();
  m = fmaxf(fmaxf(redm[0],redm[1]), fmaxf(redm[2],redm[3]));
  v.x = expf(v.x-m); v.y = expf(v.y-m); v.z = expf(v.z-m); v.w = expf(v.w-m);
  float su = v.x+v.y+v.z+v.w;
  #pragma unroll
  for (int o=32;o;o>>=1) su += __shfl_xor(su,o);
  if ((tid&63)==0) reds[tid>>6] = su;
  __syncthreads();
  su = reds[0]+reds[1]+reds[2]+reds[3];
  float inv = 1.f/su;
  v.x*=inv; v.y*=inv; v.z*=inv; v.w*=inv;
  *(float4*)&P[(size_t)i*1024 + tid*4] = v;
}

extern "C" void kernel_launch(void* const* d_in, const int* in_sizes, int n_in,
                              void* d_out, int out_size, void* d_ws, size_t ws_size,
                              hipStream_t stream)
{
  const int*   x    = (const int*)d_in[0];
  const int*   xp   = (const int*)d_in[1];
  const float* we   = (const float*)d_in[2];
  const float* pe   = (const float*)d_in[3];
  const float* Wih  = (const float*)d_in[4];   // [2][2][2048][1024]
  const float* Whh  = (const float*)d_in[5];   // [2][2][2048][512]
  const float* bl   = (const float*)d_in[6];   // [2][2][2048]
  const float* Wh   = (const float*)d_in[7];
  const float* bh   = (const float*)d_in[8];
  const float* Wd   = (const float*)d_in[9];
  const float* bd   = (const float*)d_in[10];
  const float* Wbi  = (const float*)d_in[11];
  const float* bbi  = (const float*)d_in[12];
  float* outp = (float*)d_out;

  // workspace layout (28 MB), with reuse after the scans:
  char* ws = (char*)d_ws;
  float* X0   = (float*)(ws);                  // [0,4M)   embeddings
  float* pre  = (float*)(ws + ((size_t)4<<20));// [4M,20M) input projections
  float* out0 = (float*)(ws + ((size_t)20<<20));// [20M,24M)
  float* out1 = (float*)(ws + ((size_t)24<<20));// [24M,28M)
  float* head = (float*)(ws);                  // reuse [0,4M)
  float* dep  = (float*)(ws + ((size_t)4<<20));// reuse [4M,8M)
  float* Ubuf = (float*)(ws + ((size_t)8<<20));// reuse [8M,12M)

  // sentinel-init the scan outputs (one contiguous 8MB memset)
  hipMemsetAsync(out0, 0x7F, (size_t)8<<20, stream);

  dim3 blk(256);
  k_embed<<<1024, blk, 0, stream>>>(x, xp, we, pe, X0);

  // layer 0: pre = X0 * Wih[0]^T + b[0]  (both dirs stacked: N=4096)
  k_gemm_abT<<<dim3(32,8), blk, 0, stream>>>(X0, Wih, pre, 1024, 4096, 1024, bl, nullptr);
  k_lstm_scan<<<64, dim3(512), 0, stream>>>(pre, Whh, out0);

  // layer 1
  k_gemm_abT<<<dim3(32,8), blk, 0, stream>>>(out0, Wih + (size_t)4096*1024, pre,
                                             1024, 4096, 1024, bl + 4096, nullptr);
  k_lstm_scan<<<64, dim3(512), 0, stream>>>(pre, Whh + (size_t)2*2048*512, out1);

  // biaffine: head|dep merged; U = dep*Wbi^T ; scores = head*U^T + bbi
  k_gemm_hd <<<dim3(16,8), blk, 0, stream>>>(out1, Wh, bh, head, Wd, bd, dep);
  k_gemm_abT<<<dim3(8,8), blk, 0, stream>>>(dep,  Wbi, Ubuf,1024, 1024, 1024, nullptr, nullptr);
  k_gemm_abT<<<dim3(8,8), blk, 0, stream>>>(head, Ubuf, outp,1024, 1024, 1024, nullptr, bbi);

  k_softmax<<<1024, blk, 0, stream>>>(outp);
}